// Round 2
// baseline (696.997 us; speedup 1.0000x reference)
//
#include <hip/hip_runtime.h>

// SkipLSTMCell — round 5: high-occupancy gemm (TM=32, K-split LDS, streamed B-frags).
// Pipeline unchanged: prep (pack W hi/lo, zero counter) -> classify (trivial rows +
// compaction) -> gemm (3-pass f16 Markidis MFMA on gathered active rows).
// gemm retiled: 32 rows/block, acc[8][2]=64 regs, B-fragments streamed inside the
// ntile loop (8 live regs, not 64), X staged in two K=128 halves (LDS 66KB -> 18KB).
// Target: 4 waves/SIMD (was 2). All arithmetic orders bitwise-identical to round 4.

typedef _Float16 half8  __attribute__((ext_vector_type(8)));
typedef _Float16 half4v __attribute__((ext_vector_type(4)));
typedef float    float4v __attribute__((ext_vector_type(4)));

#define B_ROWS 262144
#define TM 64               // classify tile (unchanged)
#define TG 32               // gemm rows per block
#define XPITCH_H 136        // f16 elems/row per K-half: 128 data + 8 pad (272B = 17*16B)
#define XPLANE_H (TG * XPITCH_H)   // 4352 f16 per comp plane per half
#define WCOMP  131072       // f16 elems per W component (256*512)

__device__ __forceinline__ float sigmoidf_(float v) { return 1.0f / (1.0f + __expf(-v)); }
__device__ __forceinline__ float tanhf_(float v) {
    float ax = fabsf(v);
    float t = __expf(-2.0f * ax);
    float r = (1.0f - t) / (1.0f + t);
    return copysignf(r, v);
}

// Pack W_ih|W_hh into per-lane MFMA B-fragments, f16 hi/lo components.
__global__ void prep_kernel(const float* __restrict__ W_ih, const float* __restrict__ W_hh,
                            const float* __restrict__ b_ih, const float* __restrict__ b_hh,
                            _Float16* __restrict__ Wp, float* __restrict__ bias,
                            int* __restrict__ counter) {
    if (blockIdx.x == 0 && threadIdx.x == 0) *counter = 0;   // re-zero each launch (graph-safe)
    int idx = blockIdx.x * 256 + threadIdx.x;   // [0, 131072)
    int n = idx >> 8, k = idx & 255;
    float v = (k < 128) ? W_ih[n * 128 + k] : W_hh[n * 128 + (k - 128)];
    _Float16 wh = (_Float16)v;
    _Float16 wl = (_Float16)(v - (float)wh);
    int kb = k >> 5, quad = (k >> 3) & 3, j = k & 7;
    int nt = n >> 4, n16 = n & 15, lane = quad * 16 + n16;
    int base = (kb * 32 + nt) * 512 + lane * 8 + j;
    Wp[base] = wh;
    Wp[WCOMP + base] = wl;
    if (idx < 512) bias[idx] = b_ih[idx] + b_hh[idx];
}

// Trivial rows: write outputs directly; active rows: append index to list.
__global__ void classify_kernel(const float* __restrict__ u, const float* __restrict__ h,
                                const float* __restrict__ c, const float* __restrict__ delta_u,
                                const int* __restrict__ skip, const float* __restrict__ lin_b,
                                int* __restrict__ counter, int* __restrict__ act_idx,
                                float* __restrict__ out) {
    __shared__ int s_cat[TM];     // 0=zero-fill, 1=copy, 2=active
    const int tid = threadIdx.x;
    const int m0  = blockIdx.x * TM;

    float* out_u  = out;
    float* out_h  = out + (size_t)B_ROWS;
    float* out_c  = out + (size_t)B_ROWS * 129;
    float* out_du = out + (size_t)B_ROWS * 257;
    float* out_ns = out + (size_t)B_ROWS * 258;

    if (tid < TM) {               // exactly wave 0
        int row = m0 + tid;
        float uv  = u[row];
        float duv = delta_u[row];
        int   sk  = skip[row];
        float buv = rintf(uv);    // jnp.round = round-half-even
        bool active = (sk == 0) && (buv != 0.0f);
        s_cat[tid] = active ? 2 : ((sk != 0 && buv == 0.0f) ? 1 : 0);

        if (!active) {
            float nu, duo;
            if (sk != 0) {        // keep = 1-bu
                nu  = (buv == 0.0f) ? fminf(fmaxf(uv + duv, 0.0f), 1.0f) : 0.0f;
                duo = duv;
            } else {              // skip=0, bu=0: nc*bu == 0 vector
                nu  = 0.0f;
                duo = sigmoidf_(lin_b[0]);
            }
            float nsk = ceilf(0.5f / nu) - 1.0f;
            if (!__builtin_isfinite(nsk)) nsk = 1.0e30f;   // ref emits +inf; finite passes
            out_u[row]  = nu;
            out_du[row] = duo;
            out_ns[row] = nsk;
        }
        // wave-level compaction: one atomic per block
        unsigned long long mask = __ballot(active);
        int nact = __popcll(mask);
        int base = 0;
        if (tid == 0 && nact) base = atomicAdd(counter, nact);
        base = __shfl(base, 0, 64);
        if (active) {
            int pos = __popcll(mask & ((1ull << tid) - 1ull));
            act_idx[base + pos] = row;
        }
    }
    __syncthreads();

    // h/c outputs for non-active rows: 32 threads x float4 per row, 8 rows/pass
    #pragma unroll
    for (int it = 0; it < 8; ++it) {
        int r = it * 8 + (tid >> 5);
        int cat = s_cat[r];
        if (cat == 2) continue;                  // gemm kernel writes these
        size_t m = (size_t)(m0 + r);
        int c4 = (tid & 31) * 4;
        float4v vh = {0.f, 0.f, 0.f, 0.f}, vc = {0.f, 0.f, 0.f, 0.f};
        if (cat == 1) {
            vh = *(const float4v*)&h[m * 128 + c4];
            vc = *(const float4v*)&c[m * 128 + c4];
        }
        *(float4v*)&out_h[m * 128 + c4] = vh;
        *(float4v*)&out_c[m * 128 + c4] = vc;
    }
}

__launch_bounds__(256, 4)
__global__ void gemm_kernel(const float* __restrict__ x, const float* __restrict__ h,
                            const float* __restrict__ c,
                            const float* __restrict__ lin_w, const float* __restrict__ lin_b,
                            const _Float16* __restrict__ Wp, const float* __restrict__ bias,
                            const int* __restrict__ counter, const int* __restrict__ act_idx,
                            float* __restrict__ out) {
    const int n_act = *counter;
    if ((int)blockIdx.x * TG >= n_act) return;   // worst-case grid, early-exit tail

    __shared__ __align__(16) _Float16 Xs[2 * XPLANE_H];   // [comp][row][k_half], 17KB
    __shared__ float zw[4][TG];
    __shared__ int   s_rid[TG];

    const int tid = threadIdx.x;

    if (tid < TG) {
        int g = blockIdx.x * TG + tid;
        s_rid[tid] = act_idx[g < n_act ? g : n_act - 1];  // clamp tail to a valid row
    }
    __syncthreads();

    const int lane = tid & 63, w = tid >> 6;
    const int n16 = lane & 15, quad = lane >> 4;

    int ntid[8];
    #pragma unroll
    for (int g = 0; g < 4; ++g)
        #pragma unroll
        for (int p = 0; p < 2; ++p) ntid[g * 2 + p] = w * 2 + g * 8 + p;

    float4v acc[8][2];   // [ntile][mtile] = 64 regs
    #pragma unroll
    for (int t = 0; t < 8; ++t)
        #pragma unroll
        for (int mt = 0; mt < 2; ++mt) acc[t][mt] = (float4v){0.f, 0.f, 0.f, 0.f};

    #pragma unroll 1
    for (int kh = 0; kh < 2; ++kh) {
        // ---- stage K-half: 32 rows x 128 cols f32 -> f16 hi/lo ----
        #pragma unroll
        for (int i = 0; i < 4; ++i) {
            int idx = i * 256 + tid;             // [0,1024)
            int r = idx >> 5, c4 = (idx & 31) * 4;
            size_t srow = (size_t)s_rid[r];
            float4v v;
            if (kh == 0) v = *(const float4v*)&x[srow * 128 + c4];
            else         v = *(const float4v*)&h[srow * 128 + c4];
            half4v hi, lo;
            #pragma unroll
            for (int e = 0; e < 4; ++e) {
                _Float16 hh = (_Float16)v[e];
                hi[e] = hh;
                lo[e] = (_Float16)(v[e] - (float)hh);
            }
            *(half4v*)&Xs[r * XPITCH_H + c4]             = hi;
            *(half4v*)&Xs[XPLANE_H + r * XPITCH_H + c4]  = lo;
        }
        __syncthreads();

        #pragma unroll
        for (int kbl = 0; kbl < 4; ++kbl) {
            const int kbg = kh * 4 + kbl;        // global K-block 0..7 (ascending: same
                                                 // accumulation order as round 4)
            half8 ah[2], al[2];
            const int koff = kbl * 32 + quad * 8;
            #pragma unroll
            for (int mt = 0; mt < 2; ++mt) {
                int m = mt * 16 + n16;
                ah[mt] = *(const half8*)&Xs[m * XPITCH_H + koff];
                al[mt] = *(const half8*)&Xs[XPLANE_H + m * XPITCH_H + koff];
            }
            #pragma unroll
            for (int t = 0; t < 8; ++t) {        // B-frags streamed: 8 live regs
                const _Float16* bp = Wp + (size_t)(kbg * 32 + ntid[t]) * 512 + lane * 8;
                half8 bh = *(const half8*)bp;
                half8 bl = *(const half8*)(bp + WCOMP);
                #pragma unroll
                for (int mt = 0; mt < 2; ++mt) {
                    acc[t][mt] = __builtin_amdgcn_mfma_f32_16x16x32_f16(ah[mt], bh, acc[t][mt], 0, 0, 0);
                    acc[t][mt] = __builtin_amdgcn_mfma_f32_16x16x32_f16(al[mt], bh, acc[t][mt], 0, 0, 0);
                    acc[t][mt] = __builtin_amdgcn_mfma_f32_16x16x32_f16(ah[mt], bl, acc[t][mt], 0, 0, 0);
                }
            }
        }
        __syncthreads();                         // before restaging next half
    }

    // ---- epilogue: every row here has skip==0, bu==1 ----
    float* out_u  = out;
    float* out_h  = out + (size_t)B_ROWS;
    float* out_c  = out + (size_t)B_ROWS * 129;
    float* out_du = out + (size_t)B_ROWS * 257;
    float* out_ns = out + (size_t)B_ROWS * 258;

    float zpart[2][4];
    #pragma unroll
    for (int mt = 0; mt < 2; ++mt)
        #pragma unroll
        for (int reg = 0; reg < 4; ++reg) zpart[mt][reg] = 0.f;

    #pragma unroll
    for (int p = 0; p < 2; ++p) {
        int hc = w * 32 + p * 16 + n16;
        float bi = bias[hc], bf = bias[hc + 128], bg = bias[hc + 256], bo = bias[hc + 384];
        float lw = lin_w[hc];
        #pragma unroll
        for (int mt = 0; mt < 2; ++mt) {
            #pragma unroll
            for (int reg = 0; reg < 4; ++reg) {
                int row = mt * 16 + quad * 4 + reg;
                bool valid = blockIdx.x * TG + row < n_act;
                size_t m = (size_t)s_rid[row];
                float iv = sigmoidf_(acc[0 * 2 + p][mt][reg] + bi);
                float fv = sigmoidf_(acc[1 * 2 + p][mt][reg] + bf);
                float gv = tanhf_  (acc[2 * 2 + p][mt][reg] + bg);
                float ov = sigmoidf_(acc[3 * 2 + p][mt][reg] + bo);
                float cin = c[m * 128 + hc];
                float ncv = fv * cin + iv * gv;
                float nhv = ov * tanhf_(ncv);
                if (valid) {
                    out_h[m * 128 + hc] = nhv;   // nh * bu, bu==1
                    out_c[m * 128 + hc] = ncv;
                }
                zpart[mt][reg] += ncv * lw;
            }
        }
    }

    #pragma unroll
    for (int mt = 0; mt < 2; ++mt)
        #pragma unroll
        for (int reg = 0; reg < 4; ++reg) {
            float v = zpart[mt][reg];
            v += __shfl_xor(v, 1, 64);
            v += __shfl_xor(v, 2, 64);
            v += __shfl_xor(v, 4, 64);
            v += __shfl_xor(v, 8, 64);
            if (n16 == 0) zw[w][mt * 16 + quad * 4 + reg] = v;
        }
    __syncthreads();

    if (tid < TG) {
        int row = tid;
        if (blockIdx.x * TG + row < n_act) {
            float z = zw[0][row] + zw[1][row] + zw[2][row] + zw[3][row];
            float dun = sigmoidf_(z + lin_b[0]);   // bu==1: sigmoid(nc@lin_w + lin_b)
            float nsk = ceilf(0.5f / dun) - 1.0f;
            if (!__builtin_isfinite(nsk)) nsk = 1.0e30f;
            size_t m = (size_t)s_rid[row];
            out_u[m]  = dun;                        // new_u_n = dun * bu
            out_du[m] = dun;
            out_ns[m] = nsk;
        }
    }
}

extern "C" void kernel_launch(void* const* d_in, const int* in_sizes, int n_in,
                              void* d_out, int out_size, void* d_ws, size_t ws_size,
                              hipStream_t stream) {
    const float* x     = (const float*)d_in[0];
    const float* u     = (const float*)d_in[1];
    const float* h     = (const float*)d_in[2];
    const float* c     = (const float*)d_in[3];
    const float* du    = (const float*)d_in[4];
    const int*   skip  = (const int*)d_in[5];
    const float* W_ih  = (const float*)d_in[6];
    const float* W_hh  = (const float*)d_in[7];
    const float* b_ih  = (const float*)d_in[8];
    const float* b_hh  = (const float*)d_in[9];
    const float* lin_w = (const float*)d_in[10];
    const float* lin_b = (const float*)d_in[11];
    float* outp = (float*)d_out;

    // workspace: Wp (512KB) | bias (2KB) | counter (64B) | act_idx (1MB worst-case)
    _Float16* Wp   = (_Float16*)d_ws;
    float* bias    = (float*)((char*)d_ws + 2 * WCOMP * sizeof(_Float16));
    int* counter   = (int*)((char*)d_ws + 2 * WCOMP * sizeof(_Float16) + 2048);
    int* act_idx   = (int*)((char*)d_ws + 2 * WCOMP * sizeof(_Float16) + 2048 + 64);

    prep_kernel<<<512, 256, 0, stream>>>(W_ih, W_hh, b_ih, b_hh, Wp, bias, counter);
    classify_kernel<<<B_ROWS / TM, 256, 0, stream>>>(u, h, c, du, skip, lin_b,
                                                     counter, act_idx, outp);
    gemm_kernel<<<B_ROWS / TG, 256, 0, stream>>>(x, h, c, lin_w, lin_b, Wp, bias,
                                                 counter, act_idx, outp);
}

// Round 3
// 605.190 us; speedup vs baseline: 1.1517x; 1.1517x over previous
//
#include <hip/hip_runtime.h>

// SkipLSTMCell — round 6: TG=32 gemm with full-K LDS tile + batched per-kb B-loads.
// Round-5 post-mortem: streaming bh/bl right before their MFMAs left only 2 loads
// in flight -> L2-latency-bound (MfmaUtil 9%). This round keeps the small acc
// (acc[8][2]=64 regs) but loads all 16 B-frags per K-block up front (round-4's ILP)
// and stages the whole K=256 X tile once (33KB LDS, no kh split, 2 fewer barriers).
// __launch_bounds__(256,3): ~165 VGPR -> 3 waves/SIMD.
// prep/classify unchanged from round 5 (passing). All FP orders bitwise-identical.

typedef _Float16 half8  __attribute__((ext_vector_type(8)));
typedef _Float16 half4v __attribute__((ext_vector_type(4)));
typedef float    float4v __attribute__((ext_vector_type(4)));

#define B_ROWS 262144
#define TM 64               // classify tile
#define TG 32               // gemm rows per block
#define XPITCH 264          // f16 elems/row: 256 data + 8 pad (528B = 33*16B)
#define XPLANE (TG * XPITCH)   // 8448 f16 per comp plane
#define WCOMP  131072       // f16 elems per W component (256*512)

__device__ __forceinline__ float sigmoidf_(float v) { return 1.0f / (1.0f + __expf(-v)); }
__device__ __forceinline__ float tanhf_(float v) {
    float ax = fabsf(v);
    float t = __expf(-2.0f * ax);
    float r = (1.0f - t) / (1.0f + t);
    return copysignf(r, v);
}

// Pack W_ih|W_hh into per-lane MFMA B-fragments, f16 hi/lo components.
__global__ void prep_kernel(const float* __restrict__ W_ih, const float* __restrict__ W_hh,
                            const float* __restrict__ b_ih, const float* __restrict__ b_hh,
                            _Float16* __restrict__ Wp, float* __restrict__ bias,
                            int* __restrict__ counter) {
    if (blockIdx.x == 0 && threadIdx.x == 0) *counter = 0;   // re-zero each launch (graph-safe)
    int idx = blockIdx.x * 256 + threadIdx.x;   // [0, 131072)
    int n = idx >> 8, k = idx & 255;
    float v = (k < 128) ? W_ih[n * 128 + k] : W_hh[n * 128 + (k - 128)];
    _Float16 wh = (_Float16)v;
    _Float16 wl = (_Float16)(v - (float)wh);
    int kb = k >> 5, quad = (k >> 3) & 3, j = k & 7;
    int nt = n >> 4, n16 = n & 15, lane = quad * 16 + n16;
    int base = (kb * 32 + nt) * 512 + lane * 8 + j;
    Wp[base] = wh;
    Wp[WCOMP + base] = wl;
    if (idx < 512) bias[idx] = b_ih[idx] + b_hh[idx];
}

// Trivial rows: write outputs directly; active rows: append index to list.
__global__ void classify_kernel(const float* __restrict__ u, const float* __restrict__ h,
                                const float* __restrict__ c, const float* __restrict__ delta_u,
                                const int* __restrict__ skip, const float* __restrict__ lin_b,
                                int* __restrict__ counter, int* __restrict__ act_idx,
                                float* __restrict__ out) {
    __shared__ int s_cat[TM];     // 0=zero-fill, 1=copy, 2=active
    const int tid = threadIdx.x;
    const int m0  = blockIdx.x * TM;

    float* out_u  = out;
    float* out_h  = out + (size_t)B_ROWS;
    float* out_c  = out + (size_t)B_ROWS * 129;
    float* out_du = out + (size_t)B_ROWS * 257;
    float* out_ns = out + (size_t)B_ROWS * 258;

    if (tid < TM) {               // exactly wave 0
        int row = m0 + tid;
        float uv  = u[row];
        float duv = delta_u[row];
        int   sk  = skip[row];
        float buv = rintf(uv);    // jnp.round = round-half-even
        bool active = (sk == 0) && (buv != 0.0f);
        s_cat[tid] = active ? 2 : ((sk != 0 && buv == 0.0f) ? 1 : 0);

        if (!active) {
            float nu, duo;
            if (sk != 0) {        // keep = 1-bu
                nu  = (buv == 0.0f) ? fminf(fmaxf(uv + duv, 0.0f), 1.0f) : 0.0f;
                duo = duv;
            } else {              // skip=0, bu=0: nc*bu == 0 vector
                nu  = 0.0f;
                duo = sigmoidf_(lin_b[0]);
            }
            float nsk = ceilf(0.5f / nu) - 1.0f;
            if (!__builtin_isfinite(nsk)) nsk = 1.0e30f;   // ref emits +inf; finite passes
            out_u[row]  = nu;
            out_du[row] = duo;
            out_ns[row] = nsk;
        }
        // wave-level compaction: one atomic per block
        unsigned long long mask = __ballot(active);
        int nact = __popcll(mask);
        int base = 0;
        if (tid == 0 && nact) base = atomicAdd(counter, nact);
        base = __shfl(base, 0, 64);
        if (active) {
            int pos = __popcll(mask & ((1ull << tid) - 1ull));
            act_idx[base + pos] = row;
        }
    }
    __syncthreads();

    // h/c outputs for non-active rows: 32 threads x float4 per row, 8 rows/pass
    #pragma unroll
    for (int it = 0; it < 8; ++it) {
        int r = it * 8 + (tid >> 5);
        int cat = s_cat[r];
        if (cat == 2) continue;                  // gemm kernel writes these
        size_t m = (size_t)(m0 + r);
        int c4 = (tid & 31) * 4;
        float4v vh = {0.f, 0.f, 0.f, 0.f}, vc = {0.f, 0.f, 0.f, 0.f};
        if (cat == 1) {
            vh = *(const float4v*)&h[m * 128 + c4];
            vc = *(const float4v*)&c[m * 128 + c4];
        }
        *(float4v*)&out_h[m * 128 + c4] = vh;
        *(float4v*)&out_c[m * 128 + c4] = vc;
    }
}

__launch_bounds__(256, 3)
__global__ void gemm_kernel(const float* __restrict__ x, const float* __restrict__ h,
                            const float* __restrict__ c,
                            const float* __restrict__ lin_w, const float* __restrict__ lin_b,
                            const _Float16* __restrict__ Wp, const float* __restrict__ bias,
                            const int* __restrict__ counter, const int* __restrict__ act_idx,
                            float* __restrict__ out) {
    const int n_act = *counter;
    if ((int)blockIdx.x * TG >= n_act) return;   // worst-case grid, early-exit tail

    __shared__ __align__(16) _Float16 Xs[2 * XPLANE];   // [comp][row][k] f16, 33KB
    __shared__ float zw[4][TG];
    __shared__ int   s_rid[TG];

    const int tid = threadIdx.x;

    if (tid < TG) {
        int g = blockIdx.x * TG + tid;
        s_rid[tid] = act_idx[g < n_act ? g : n_act - 1];  // clamp tail to a valid row
    }
    __syncthreads();

    // ---- stage x|h -> LDS as f16 hi/lo, [row][k], full K=256 ----
    #pragma unroll
    for (int i = 0; i < 8; ++i) {
        int idx = i * 256 + tid;                 // [0, 2048) float4s
        int r = idx >> 6, c4 = (idx & 63) * 4;
        size_t srow = (size_t)s_rid[r];
        float4v v;
        if (c4 < 128) v = *(const float4v*)&x[srow * 128 + c4];
        else          v = *(const float4v*)&h[srow * 128 + (c4 - 128)];
        half4v hi, lo;
        #pragma unroll
        for (int e = 0; e < 4; ++e) {
            _Float16 hh = (_Float16)v[e];
            hi[e] = hh;
            lo[e] = (_Float16)(v[e] - (float)hh);
        }
        *(half4v*)&Xs[r * XPITCH + c4]          = hi;
        *(half4v*)&Xs[XPLANE + r * XPITCH + c4] = lo;
    }
    __syncthreads();

    const int lane = tid & 63, w = tid >> 6;
    const int n16 = lane & 15, quad = lane >> 4;

    int ntid[8];
    #pragma unroll
    for (int g = 0; g < 4; ++g)
        #pragma unroll
        for (int p = 0; p < 2; ++p) ntid[g * 2 + p] = w * 2 + g * 8 + p;

    float4v acc[8][2];   // [ntile][mtile] = 64 regs
    #pragma unroll
    for (int t = 0; t < 8; ++t)
        #pragma unroll
        for (int mt = 0; mt < 2; ++mt) acc[t][mt] = (float4v){0.f, 0.f, 0.f, 0.f};

    #pragma unroll 1
    for (int kb = 0; kb < 8; ++kb) {
        // batched B-frag loads: 16 dwordx4 in flight before any MFMA
        half8 bh[8], bl[8];
        #pragma unroll
        for (int t = 0; t < 8; ++t) {
            const _Float16* bp = Wp + (size_t)(kb * 32 + ntid[t]) * 512 + lane * 8;
            bh[t] = *(const half8*)bp;
            bl[t] = *(const half8*)(bp + WCOMP);
        }
        half8 ah[2], al[2];
        const int koff = kb * 32 + quad * 8;
        #pragma unroll
        for (int mt = 0; mt < 2; ++mt) {
            int m = mt * 16 + n16;
            ah[mt] = *(const half8*)&Xs[m * XPITCH + koff];
            al[mt] = *(const half8*)&Xs[XPLANE + m * XPITCH + koff];
        }
        #pragma unroll
        for (int t = 0; t < 8; ++t)
            #pragma unroll
            for (int mt = 0; mt < 2; ++mt) {
                acc[t][mt] = __builtin_amdgcn_mfma_f32_16x16x32_f16(ah[mt], bh[t], acc[t][mt], 0, 0, 0);
                acc[t][mt] = __builtin_amdgcn_mfma_f32_16x16x32_f16(al[mt], bh[t], acc[t][mt], 0, 0, 0);
                acc[t][mt] = __builtin_amdgcn_mfma_f32_16x16x32_f16(ah[mt], bl[t], acc[t][mt], 0, 0, 0);
            }
    }

    // ---- epilogue: every row here has skip==0, bu==1 ----
    float* out_u  = out;
    float* out_h  = out + (size_t)B_ROWS;
    float* out_c  = out + (size_t)B_ROWS * 129;
    float* out_du = out + (size_t)B_ROWS * 257;
    float* out_ns = out + (size_t)B_ROWS * 258;

    float zpart[2][4];
    #pragma unroll
    for (int mt = 0; mt < 2; ++mt)
        #pragma unroll
        for (int reg = 0; reg < 4; ++reg) zpart[mt][reg] = 0.f;

    #pragma unroll
    for (int p = 0; p < 2; ++p) {
        int hc = w * 32 + p * 16 + n16;
        float bi = bias[hc], bf = bias[hc + 128], bg = bias[hc + 256], bo = bias[hc + 384];
        float lw = lin_w[hc];
        #pragma unroll
        for (int mt = 0; mt < 2; ++mt) {
            #pragma unroll
            for (int reg = 0; reg < 4; ++reg) {
                int row = mt * 16 + quad * 4 + reg;
                bool valid = blockIdx.x * TG + row < n_act;
                size_t m = (size_t)s_rid[row];
                float iv = sigmoidf_(acc[0 * 2 + p][mt][reg] + bi);
                float fv = sigmoidf_(acc[1 * 2 + p][mt][reg] + bf);
                float gv = tanhf_  (acc[2 * 2 + p][mt][reg] + bg);
                float ov = sigmoidf_(acc[3 * 2 + p][mt][reg] + bo);
                float cin = c[m * 128 + hc];
                float ncv = fv * cin + iv * gv;
                float nhv = ov * tanhf_(ncv);
                if (valid) {
                    out_h[m * 128 + hc] = nhv;   // nh * bu, bu==1
                    out_c[m * 128 + hc] = ncv;
                }
                zpart[mt][reg] += ncv * lw;
            }
        }
    }

    #pragma unroll
    for (int mt = 0; mt < 2; ++mt)
        #pragma unroll
        for (int reg = 0; reg < 4; ++reg) {
            float v = zpart[mt][reg];
            v += __shfl_xor(v, 1, 64);
            v += __shfl_xor(v, 2, 64);
            v += __shfl_xor(v, 4, 64);
            v += __shfl_xor(v, 8, 64);
            if (n16 == 0) zw[w][mt * 16 + quad * 4 + reg] = v;
        }
    __syncthreads();

    if (tid < TG) {
        int row = tid;
        if (blockIdx.x * TG + row < n_act) {
            float z = zw[0][row] + zw[1][row] + zw[2][row] + zw[3][row];
            float dun = sigmoidf_(z + lin_b[0]);   // bu==1: sigmoid(nc@lin_w + lin_b)
            float nsk = ceilf(0.5f / dun) - 1.0f;
            if (!__builtin_isfinite(nsk)) nsk = 1.0e30f;
            size_t m = (size_t)s_rid[row];
            out_u[m]  = dun;                        // new_u_n = dun * bu
            out_du[m] = dun;
            out_ns[m] = nsk;
        }
    }
}

extern "C" void kernel_launch(void* const* d_in, const int* in_sizes, int n_in,
                              void* d_out, int out_size, void* d_ws, size_t ws_size,
                              hipStream_t stream) {
    const float* x     = (const float*)d_in[0];
    const float* u     = (const float*)d_in[1];
    const float* h     = (const float*)d_in[2];
    const float* c     = (const float*)d_in[3];
    const float* du    = (const float*)d_in[4];
    const int*   skip  = (const int*)d_in[5];
    const float* W_ih  = (const float*)d_in[6];
    const float* W_hh  = (const float*)d_in[7];
    const float* b_ih  = (const float*)d_in[8];
    const float* b_hh  = (const float*)d_in[9];
    const float* lin_w = (const float*)d_in[10];
    const float* lin_b = (const float*)d_in[11];
    float* outp = (float*)d_out;

    // workspace: Wp (512KB) | bias (2KB) | counter (64B) | act_idx (1MB worst-case)
    _Float16* Wp   = (_Float16*)d_ws;
    float* bias    = (float*)((char*)d_ws + 2 * WCOMP * sizeof(_Float16));
    int* counter   = (int*)((char*)d_ws + 2 * WCOMP * sizeof(_Float16) + 2048);
    int* act_idx   = (int*)((char*)d_ws + 2 * WCOMP * sizeof(_Float16) + 2048 + 64);

    prep_kernel<<<512, 256, 0, stream>>>(W_ih, W_hh, b_ih, b_hh, Wp, bias, counter);
    classify_kernel<<<B_ROWS / TM, 256, 0, stream>>>(u, h, c, du, skip, lin_b,
                                                     counter, act_idx, outp);
    gemm_kernel<<<B_ROWS / TG, 256, 0, stream>>>(x, h, c, lin_w, lin_b, Wp, bias,
                                                 counter, act_idx, outp);
}